// Round 1
// baseline (203.697 us; speedup 1.0000x reference)
//
#include <hip/hip_runtime.h>

// DistancePredictor on MI355X (gfx950).
// Decomposition: A = X@(Wi+Wd), Bm = X@(Wj-Wd)+b1 (prep, MFMA),
// P[b,i,j,h] = sum_d X[b,i,d]X[b,j,d]Wp[d,h] (main, bf16 MFMA, triangular tiles),
// out = 0.5*(relu(W2.gelu(A_i+Bm_j+P)+b2) + relu(W2.gelu(A_j+Bm_i+P)+b2)), diag=0.
// P is symmetric in (i,j): compute only ti<=tj tiles, emit both orientations.

typedef __attribute__((ext_vector_type(8))) short short8;
typedef __attribute__((ext_vector_type(16))) float f32x16;

#define NT 32            // 1024 / 32 tiles per dim
#define NTRI 528         // NT*(NT+1)/2

__device__ __forceinline__ unsigned short f2bf(float f) {
  unsigned int u = __float_as_uint(f);
  u = (u + 0x7fffu + ((u >> 16) & 1u)) >> 16;   // RNE
  return (unsigned short)u;
}

__device__ __forceinline__ short8 pack8(float4 a, float4 b) {
  short8 r;
  r[0] = (short)f2bf(a.x); r[1] = (short)f2bf(a.y);
  r[2] = (short)f2bf(a.z); r[3] = (short)f2bf(a.w);
  r[4] = (short)f2bf(b.x); r[5] = (short)f2bf(b.y);
  r[6] = (short)f2bf(b.z); r[7] = (short)f2bf(b.w);
  return r;
}

// tanh-form GELU: gelu(x) = x*(1 - 1/(exp2(2*log2e*u)+1)), u = x*(c + c*a*x^2)
// max |dev| vs exact erf-GELU ~5e-4 << 5.16e-2 threshold.
__device__ __forceinline__ float gelu_f(float x) {
  float t = x * x;
  float u = x * fmaf(0.0356774081f, t, 0.7978845608f);
  float e = __builtin_amdgcn_exp2f(u * 2.885390082f);
  float r = __builtin_amdgcn_rcpf(e + 1.0f);
  return fmaf(-x, r, x);
}

// ---- k0: build WsumT/WdiffT/WpT as bf16 [h][d] (transposed) into ws ----
// wsT layout (ushort): [0..16383]=WsumT, [16384..32767]=WdiffT, [32768..49151]=WpT
__global__ void k0_prep_w(const float* __restrict__ W1, unsigned short* __restrict__ wsT) {
  int idx = blockIdx.x * 256 + threadIdx.x;          // grid = 192 blocks exactly
  int arr = idx >> 14, rem = idx & 16383, h = rem >> 7, d = rem & 127;
  float v;
  if (arr == 0)      v = W1[d * 128 + h] + W1[(256 + d) * 128 + h];   // Wi + Wd
  else if (arr == 1) v = W1[(128 + d) * 128 + h] - W1[(256 + d) * 128 + h]; // Wj - Wd
  else               v = W1[(384 + d) * 128 + h];                     // Wp
  wsT[idx] = f2bf(v);
}

// ---- k1: A = X@Wsum, Bm = X@Wdiff + b1  (rows 2048, cols 128+128) via MFMA ----
__global__ __launch_bounds__(256) void k1_ab(const float* __restrict__ X,
                                             const unsigned short* __restrict__ wsT,
                                             const float* __restrict__ b1,
                                             float* __restrict__ Aout,
                                             float* __restrict__ Bout) {
  int tid = threadIdx.x, w = tid >> 6, lane = tid & 63, jl = lane & 31, hi = lane >> 5;
  int row0 = blockIdx.x * 64;     // 32 blocks x 64 X-rows
  int c0 = w * 64;                // wave -> 64 of the 256 output cols (0..127 A, 128..255 Bm)
  f32x16 a00 = (f32x16)0.f, a01 = (f32x16)0.f, a10 = (f32x16)0.f, a11 = (f32x16)0.f;
#pragma unroll
  for (int s = 0; s < 8; ++s) {
    const float* xp0 = X + (size_t)(row0 + jl) * 128 + s * 16 + hi * 8;
    const float* xp1 = xp0 + 32 * 128;
    short8 fa0 = pack8(*(const float4*)xp0, *(const float4*)(xp0 + 4));
    short8 fa1 = pack8(*(const float4*)xp1, *(const float4*)(xp1 + 4));
    short8 fb0 = *(const short8*)(wsT + (size_t)(c0 + jl) * 128 + s * 16 + hi * 8);
    short8 fb1 = *(const short8*)(wsT + (size_t)(c0 + 32 + jl) * 128 + s * 16 + hi * 8);
    a00 = __builtin_amdgcn_mfma_f32_32x32x16_bf16(fa0, fb0, a00, 0, 0, 0);
    a01 = __builtin_amdgcn_mfma_f32_32x32x16_bf16(fa0, fb1, a01, 0, 0, 0);
    a10 = __builtin_amdgcn_mfma_f32_32x32x16_bf16(fa1, fb0, a10, 0, 0, 0);
    a11 = __builtin_amdgcn_mfma_f32_32x32x16_bf16(fa1, fb1, a11, 0, 0, 0);
  }
  bool isB = (c0 >= 128);
  float b1v0 = 0.f, b1v1 = 0.f;
  if (isB) { b1v0 = b1[c0 - 128 + jl]; b1v1 = b1[c0 - 96 + jl]; }
#pragma unroll
  for (int q = 0; q < 16; ++q) {
    int r = (q & 3) + 8 * (q >> 2) + 4 * hi;       // C/D row map (m74/m101)
    int bl0 = row0 + r, bl1 = row0 + 32 + r;
    if (!isB) {
      Aout[(size_t)bl0 * 128 + c0 + jl]      = a00[q];
      Aout[(size_t)bl0 * 128 + c0 + 32 + jl] = a01[q];
      Aout[(size_t)bl1 * 128 + c0 + jl]      = a10[q];
      Aout[(size_t)bl1 * 128 + c0 + 32 + jl] = a11[q];
    } else {
      Bout[(size_t)bl0 * 128 + c0 - 128 + jl] = a00[q] + b1v0;
      Bout[(size_t)bl0 * 128 + c0 - 96 + jl]  = a01[q] + b1v1;
      Bout[(size_t)bl1 * 128 + c0 - 128 + jl] = a10[q] + b1v0;
      Bout[(size_t)bl1 * 128 + c0 - 96 + jl]  = a11[q] + b1v1;
    }
  }
}

// ---- k2: main triangular-tile kernel ----
// Per block: tile (b, ti<=tj), 32 i-rows x 32 j-rows. Per i: build M[j,d]=Xi[d]*Xj[d]
// (bf16, LDS, XOR-swizzled), D[h,j] = WpT @ M^T via 8x mfma_32x32x16_bf16 with
// h split across 4 waves, then dual-orientation gelu/W2-dot epilogue.
__global__ __launch_bounds__(256, 2) void k2_main(const float* __restrict__ X,
                                                  const unsigned short* __restrict__ WpT,
                                                  const float* __restrict__ Aws,
                                                  const float* __restrict__ Bws,
                                                  const float* __restrict__ W2,
                                                  const float* __restrict__ b2,
                                                  float* __restrict__ out) {
  __shared__ __align__(16) unsigned short Mlds[32 * 128];  // 8 KB: M[j][d] bf16, swizzled
  __shared__ float red0[4][32], red1[4][32];
  __shared__ float valbuf[32][32];

  int bid = blockIdx.x;
  int b = bid / NTRI;
  int t = bid - b * NTRI;
  int ti = 0;
  while (t >= NT - ti) { t -= NT - ti; ++ti; }
  int tj = ti + t;
  int gi0 = ti * 32, gj0 = tj * 32;

  int tid = threadIdx.x, w = tid >> 6, lane = tid & 63, jl = lane & 31, hi = lane >> 5;
  int dseg = tid >> 5;                      // 0..7 : 16-d slice owned for M-build
  int gj = gj0 + jl;

  // persistent per-thread state
  float xj[16], bmj[16], ajv[16], w2h[16];
  {
    const float* xjp = X + ((size_t)b * 1024 + gj0 + (tid & 31)) * 128 + dseg * 16;
    *(float4*)(xj + 0)  = *(const float4*)(xjp + 0);
    *(float4*)(xj + 4)  = *(const float4*)(xjp + 4);
    *(float4*)(xj + 8)  = *(const float4*)(xjp + 8);
    *(float4*)(xj + 12) = *(const float4*)(xjp + 12);
  }
#pragma unroll
  for (int g = 0; g < 4; ++g) {
    int hb = 8 * g + 4 * hi + 32 * w;       // h-base for regs q=4g..4g+3
    *(float4*)(bmj + 4 * g) = *(const float4*)(Bws + (size_t)(b * 1024 + gj) * 128 + hb);
    *(float4*)(ajv + 4 * g) = *(const float4*)(Aws + (size_t)(b * 1024 + gj) * 128 + hb);
    *(float4*)(w2h + 4 * g) = *(const float4*)(W2 + hb);
  }
  short8 afrag[8];                          // WpT A-frags for this wave's h-tile
#pragma unroll
  for (int s = 0; s < 8; ++s)
    afrag[s] = *(const short8*)(WpT + (size_t)(w * 32 + jl) * 128 + s * 16 + hi * 8);
  float b2s = b2[0];

  char* mldsB = (char*)Mlds;
  int wr_base = (tid & 31) * 256;
  int swz = ((tid & 31) & 7) << 4;          // G4 XOR swizzle on 16B units

#pragma unroll 1
  for (int i = 0; i < 32; ++i) {
    int gi = gi0 + i;
    // --- phase 1: loads + M build ---
    float xiv[16], aiv[16], biv[16];
    const float* xip = X + ((size_t)b * 1024 + gi) * 128 + dseg * 16;
    *(float4*)(xiv + 0)  = *(const float4*)(xip + 0);
    *(float4*)(xiv + 4)  = *(const float4*)(xip + 4);
    *(float4*)(xiv + 8)  = *(const float4*)(xip + 8);
    *(float4*)(xiv + 12) = *(const float4*)(xip + 12);
#pragma unroll
    for (int g = 0; g < 4; ++g) {           // epilogue biases: issue early, use post-MFMA
      int hb = 8 * g + 4 * hi + 32 * w;
      *(float4*)(aiv + 4 * g) = *(const float4*)(Aws + (size_t)(b * 1024 + gi) * 128 + hb);
      *(float4*)(biv + 4 * g) = *(const float4*)(Bws + (size_t)(b * 1024 + gi) * 128 + hb);
    }
    union { unsigned short us[16]; short8 v[2]; } mb;
#pragma unroll
    for (int r = 0; r < 16; ++r) mb.us[r] = f2bf(xiv[r] * xj[r]);
    *(short8*)(mldsB + wr_base + ((dseg * 32 + 0) ^ swz))  = mb.v[0];
    *(short8*)(mldsB + wr_base + ((dseg * 32 + 16) ^ swz)) = mb.v[1];
    __syncthreads();

    // --- phase 2: P tile, D[h(32 per wave), j(32)] ---
    f32x16 acc = (f32x16)0.0f;
#pragma unroll
    for (int s = 0; s < 8; ++s) {
      short8 bf = *(const short8*)(mldsB + wr_base + (((2 * s + hi) * 16) ^ swz));
      acc = __builtin_amdgcn_mfma_f32_32x32x16_bf16(afrag[s], bf, acc, 0, 0, 0);
    }

    // --- phase 3: dual-orientation gelu + W2 dot ---
    float o1a = 0.f, o1b = 0.f, o2a = 0.f, o2b = 0.f;
#pragma unroll
    for (int q = 0; q < 16; ++q) {
      float p  = acc[q];
      float z1 = p + aiv[q] + bmj[q];       // raw[gi, gj] orientation
      float z2 = p + ajv[q] + biv[q];       // raw[gj, gi] orientation
      float g1 = gelu_f(z1), g2 = gelu_f(z2);
      float wq = w2h[q];
      if (q & 1) { o1b = fmaf(g1, wq, o1b); o2b = fmaf(g2, wq, o2b); }
      else       { o1a = fmaf(g1, wq, o1a); o2a = fmaf(g2, wq, o2a); }
    }
    float o1 = o1a + o1b, o2 = o2a + o2b;
    o1 += __shfl_xor(o1, 32);
    o2 += __shfl_xor(o2, 32);
    if (lane < 32) { red0[w][lane] = o1; red1[w][lane] = o2; }
    __syncthreads();

    // --- phase 4: cross-wave combine, relu, symmetrize, row store ---
    if (tid < 32) {
      float s1 = red0[0][tid] + red0[1][tid] + red0[2][tid] + red0[3][tid] + b2s;
      float s2 = red1[0][tid] + red1[1][tid] + red1[2][tid] + red1[3][tid] + b2s;
      float v = 0.5f * (fmaxf(s1, 0.f) + fmaxf(s2, 0.f));
      if (ti == tj && tid == i) v = 0.f;    // zero diagonal
      out[((size_t)b * 1024 + gi) * 1024 + gj0 + tid] = v;
      valbuf[i][tid] = v;
    }
  }

  __syncthreads();
  if (ti != tj) {                           // coalesced transposed flush of mirror block
    int j = tid & 31, i0 = (tid >> 5) * 4;
    float4 v;
    v.x = valbuf[i0 + 0][j]; v.y = valbuf[i0 + 1][j];
    v.z = valbuf[i0 + 2][j]; v.w = valbuf[i0 + 3][j];
    *(float4*)(out + ((size_t)b * 1024 + gj0 + j) * 1024 + gi0 + i0) = v;
  }
}

extern "C" void kernel_launch(void* const* d_in, const int* in_sizes, int n_in,
                              void* d_out, int out_size, void* d_ws, size_t ws_size,
                              hipStream_t stream) {
  (void)in_sizes; (void)n_in; (void)out_size; (void)ws_size;
  const float* X  = (const float*)d_in[0];   // (2,1024,128)
  const float* W1 = (const float*)d_in[1];   // (512,128)
  const float* b1 = (const float*)d_in[2];   // (128)
  const float* W2 = (const float*)d_in[3];   // (128,1)
  const float* b2 = (const float*)d_in[4];   // (1)
  float* out = (float*)d_out;                // (2,1024,1024)

  // ws: [0,98304) bf16 WsumT/WdiffT/WpT; [98304,+1MB) A f32; then Bm f32. ~2.1 MB.
  unsigned short* wsT = (unsigned short*)d_ws;
  unsigned short* WpT = wsT + 2 * 16384;
  float* Aws = (float*)((char*)d_ws + 98304);
  float* Bws = (float*)((char*)d_ws + 98304 + 1048576);

  k0_prep_w<<<192, 256, 0, stream>>>(W1, wsT);
  k1_ab<<<32, 256, 0, stream>>>(X, wsT, b1, Aws, Bws);
  k2_main<<<2 * NTRI, 256, 0, stream>>>(X, WpT, Aws, Bws, W2, b2, out);
}